// Round 16
// baseline (222.583 us; speedup 1.0000x reference)
//
#include <hip/hip_runtime.h>

#define NN 100000
#define NE 1600000
#define DD 64
#define NGRP 6250   // NN/16
#define NBGRU 1563  // ceil(NGRP/4)
#define NBKT 391    // buckets of 256 dst nodes (ceil(NN/256))
#define BCAP 4608   // per-bucket capacity: mean 4092, sd 64 -> +8 sigma (HW-validated)
#define BCH  4096   // edges per bin_k block
#define NBIN 391    // ceil(NE/BCH)
#define OVCAP 4096  // overflow capacity (never hit in practice)

typedef __attribute__((ext_vector_type(8))) short short8_t;
typedef __attribute__((ext_vector_type(4))) float f32x4;

__device__ __forceinline__ float fsig(float x) {
    return __fdividef(1.0f, 1.0f + __expf(-x));
}
__device__ __forceinline__ float ftanh(float x) {
    return __fdividef(2.0f, 1.0f + __expf(-2.0f * x)) - 1.0f;
}
__device__ __forceinline__ unsigned int bf16rne(float a) {
    unsigned int u = __float_as_uint(a);
    return (u + 0x7fffu + ((u >> 16) & 1u)) >> 16;
}
__device__ __forceinline__ short8_t pack8(float4 a, float4 b) {
    short8_t r;
    r[0] = (short)bf16rne(a.x); r[1] = (short)bf16rne(a.y);
    r[2] = (short)bf16rne(a.z); r[3] = (short)bf16rne(a.w);
    r[4] = (short)bf16rne(b.x); r[5] = (short)bf16rne(b.y);
    r[6] = (short)bf16rne(b.z); r[7] = (short)bf16rne(b.w);
    return r;
}

// ---- hcvt_k: bf16 mirror of h (12.8 MB; halves gather bytes, 2x L2 fit) --
__global__ __launch_bounds__(256) void hcvt_k(const float* __restrict__ h,
                                              unsigned* __restrict__ hb) {
    const int i = blockIdx.x * 256 + threadIdx.x;   // 12500*256 == NN*32 exactly
    const float2 v = *(const float2*)(h + (size_t)i * 2);
    hb[i] = bf16rne(v.x) | (bf16rne(v.y) << 16);
}

// ---- bin_k: LDS-staged bucket binning, 512 threads (8 waves) ------------
// Bucket b = dst>>8. Payload split: key = src | dlocal<<17 (u32), wgt = bf16.
// 6 B/edge (was 8) -> frees room for the hb mirror and cuts flush traffic.
__global__ __launch_bounds__(512) void bin_k(const int* __restrict__ src,
                                             const int* __restrict__ dst,
                                             const float* __restrict__ ew,
                                             unsigned* __restrict__ gcnt,
                                             unsigned* __restrict__ binkey,
                                             unsigned short* __restrict__ binwgt,
                                             unsigned* __restrict__ ovcnt,
                                             unsigned* __restrict__ ov_key,
                                             unsigned short* __restrict__ ov_wgt,
                                             unsigned* __restrict__ ov_b) {
    __shared__ unsigned cnt[NBKT];
    __shared__ unsigned cur[NBKT];
    __shared__ unsigned offb[NBKT];
    __shared__ unsigned gbase[NBKT];
    __shared__ unsigned ssc[512];
    __shared__ unsigned stage_key[BCH];
    __shared__ unsigned short stage_wgt[BCH];
    __shared__ unsigned short sbkt[BCH];

    const int t = threadIdx.x;
    const int e0 = blockIdx.x * BCH;
    const int M = min(BCH, NE - e0);

    for (int i = t; i < NBKT; i += 512) cnt[i] = 0;
    __syncthreads();

    for (int i = t; i < M; i += 512) {
        const unsigned b = ((unsigned)dst[e0 + i]) >> 8;
        atomicAdd(&cnt[b], 1u);
    }
    __syncthreads();

    {
        const unsigned v = (t < NBKT) ? cnt[t] : 0u;
        ssc[t] = v;
        __syncthreads();
        for (int o = 1; o < 512; o <<= 1) {
            const unsigned tmp = (t >= o) ? ssc[t - o] : 0u;
            __syncthreads();
            ssc[t] += tmp;
            __syncthreads();
        }
        if (t < NBKT) { offb[t] = ssc[t] - v; cur[t] = ssc[t] - v; }
    }
    __syncthreads();

    for (int i = t; i < M; i += 512) {
        const int d = dst[e0 + i];
        const unsigned b = ((unsigned)d) >> 8;
        const unsigned p = atomicAdd(&cur[b], 1u);
        stage_key[p] = (unsigned)src[e0 + i] | (((unsigned)(d & 255)) << 17);
        stage_wgt[p] = (unsigned short)bf16rne(ew[e0 + i]);
        sbkt[p] = (unsigned short)b;
    }
    __syncthreads();

    for (int i = t; i < NBKT; i += 512) {
        const unsigned c = cnt[i];
        gbase[i] = c ? atomicAdd(&gcnt[i], c) : 0u;
    }
    __syncthreads();

    for (int i = t; i < M; i += 512) {
        const unsigned b = sbkt[i];
        const unsigned gp = gbase[b] + ((unsigned)i - offb[b]);
        if (gp < BCAP) {
            binkey[b * BCAP + gp] = stage_key[i];
            binwgt[b * BCAP + gp] = stage_wgt[i];
        } else {                                    // ~never: +8 sigma margin
            const unsigned op = atomicAdd(ovcnt, 1u);
            if (op < OVCAP) {
                ov_key[op] = stage_key[i];
                ov_wgt[op] = stage_wgt[i];
                ov_b[op] = b;
            }
        }
    }
}

// ---- sort_k: in-place exact sort within each bucket + CSR emit ----------
// One block (512 threads) per bucket; all reads precede the flush back.
__global__ __launch_bounds__(512) void sort_k(unsigned* __restrict__ binkey,
                                              unsigned short* __restrict__ binwgt,
                                              const unsigned* __restrict__ gcnt,
                                              const unsigned* __restrict__ ovcnt,
                                              const unsigned* __restrict__ ov_key,
                                              const unsigned short* __restrict__ ov_wgt,
                                              const unsigned* __restrict__ ov_b,
                                              unsigned* __restrict__ cursor,
                                              unsigned* __restrict__ deg) {
    __shared__ unsigned hcnt[256];
    __shared__ unsigned off[256];
    __shared__ unsigned cur[256];
    __shared__ unsigned ssc[256];
    __shared__ unsigned stage_key[BCAP];        // 18,432 B
    __shared__ unsigned short stage_wgt[BCAP];  //  9,216 B

    const int t = threadIdx.x;
    const int b = blockIdx.x;
    const unsigned base = (unsigned)b * BCAP;
    const unsigned cnt = min(gcnt[b], (unsigned)BCAP);
    const unsigned oc = min(*ovcnt, (unsigned)OVCAP);

    if (t < 256) hcnt[t] = 0;
    __syncthreads();

    for (unsigned i = t; i < cnt; i += 512)
        atomicAdd(&hcnt[binkey[base + i] >> 17], 1u);
    for (unsigned i = t; i < oc; i += 512)
        if (ov_b[i] == (unsigned)b) atomicAdd(&hcnt[ov_key[i] >> 17], 1u);
    __syncthreads();

    unsigned v = 0;
    if (t < 256) { v = hcnt[t]; ssc[t] = v; }
    __syncthreads();
    for (int o = 1; o < 256; o <<= 1) {
        unsigned tmp = 0;
        if (t < 256 && t >= o) tmp = ssc[t - o];
        __syncthreads();
        if (t < 256) ssc[t] += tmp;
        __syncthreads();
    }
    if (t < 256) { off[t] = ssc[t] - v; cur[t] = ssc[t] - v; }
    __syncthreads();

    const int nb = min(256, NN - b * 256);
    if (t < nb) {
        const int node = b * 256 + t;
        deg[node] = hcnt[t];
        cursor[node] = base + off[t] + hcnt[t];
    }

    for (unsigned i = t; i < cnt; i += 512) {
        const unsigned k = binkey[base + i];
        const unsigned short w = binwgt[base + i];
        const unsigned p = atomicAdd(&cur[k >> 17], 1u);
        if (p < (unsigned)BCAP) { stage_key[p] = k; stage_wgt[p] = w; }
    }
    for (unsigned i = t; i < oc; i += 512) {
        if (ov_b[i] == (unsigned)b) {
            const unsigned k = ov_key[i];
            const unsigned p = atomicAdd(&cur[k >> 17], 1u);
            if (p < (unsigned)BCAP) { stage_key[p] = k; stage_wgt[p] = ov_wgt[i]; }
        }
    }
    __syncthreads();

    const unsigned tot = min(ssc[255], (unsigned)BCAP);
    for (unsigned i = t; i < tot; i += 512) {
        binkey[base + i] = stage_key[i];
        binwgt[base + i] = stage_wgt[i];
    }
}

// ---- Segment sum, bf16 gathers, 8 edges in flight per wave --------------
// Was f32 gathers: 69us, 3.07 TB/s L2-miss traffic, MLP-doubling neutral ->
// random-gather BW ceiling. bf16 rows = 128 B/row halves the miss bytes.
// lane l: edge slots {g, g+4} (g=l>>4), channels 4*(l&15)..+3 via uint2.
__global__ __launch_bounds__(256) void segsum_k(const unsigned* __restrict__ hb,
                                                const unsigned* __restrict__ binkey,
                                                const unsigned short* __restrict__ binwgt,
                                                const unsigned* __restrict__ cursor,
                                                const unsigned* __restrict__ deg,
                                                float* __restrict__ hnew) {
    const int node = blockIdx.x * 4 + (threadIdx.x >> 6);   // 25000*4 == NN
    const int lane = threadIdx.x & 63;
    const unsigned end = cursor[node];
    const unsigned len = deg[node];
    const unsigned start = end - len;
    const unsigned g = (unsigned)(lane >> 4);   // edge slot 0..3
    const int c2 = (lane & 15) << 1;            // dword offset in row (2ch/dword)

    float4 acc  = make_float4(0.f, 0.f, 0.f, 0.f);
    float4 acc2 = make_float4(0.f, 0.f, 0.f, 0.f);
    for (unsigned base = start; base < end; base += 8) {
        const unsigned e0 = base + g;
        const unsigned e1 = base + 4 + g;
        if (e0 < end) {
            const unsigned k = binkey[e0];
            const float w = __uint_as_float(((unsigned)binwgt[e0]) << 16);
            const uint2 u = *(const uint2*)(hb + (((size_t)(k & 0x1ffffu)) << 5) + c2);
            acc.x = fmaf(w, __uint_as_float(u.x << 16),          acc.x);
            acc.y = fmaf(w, __uint_as_float(u.x & 0xffff0000u),  acc.y);
            acc.z = fmaf(w, __uint_as_float(u.y << 16),          acc.z);
            acc.w = fmaf(w, __uint_as_float(u.y & 0xffff0000u),  acc.w);
        }
        if (e1 < end) {
            const unsigned k = binkey[e1];
            const float w = __uint_as_float(((unsigned)binwgt[e1]) << 16);
            const uint2 u = *(const uint2*)(hb + (((size_t)(k & 0x1ffffu)) << 5) + c2);
            acc2.x = fmaf(w, __uint_as_float(u.x << 16),          acc2.x);
            acc2.y = fmaf(w, __uint_as_float(u.x & 0xffff0000u),  acc2.y);
            acc2.z = fmaf(w, __uint_as_float(u.y << 16),          acc2.z);
            acc2.w = fmaf(w, __uint_as_float(u.y & 0xffff0000u),  acc2.w);
        }
    }
    acc.x += acc2.x; acc.y += acc2.y; acc.z += acc2.z; acc.w += acc2.w;
    #pragma unroll
    for (int off = 16; off < 64; off <<= 1) {
        acc.x += __shfl_xor(acc.x, off);
        acc.y += __shfl_xor(acc.y, off);
        acc.z += __shfl_xor(acc.z, off);
        acc.w += __shfl_xor(acc.w, off);
    }
    if (lane < 16) *(float4*)(hnew + ((size_t)node << 6) + ((lane & 15) << 2)) = acc;
}

// ---- Weight prep: pack Wih/Whh into MFMA B-fragment order (bf16) --------
__global__ __launch_bounds__(256) void wprep_k(const float* __restrict__ Wih,
                                               const float* __restrict__ Whh,
                                               unsigned* __restrict__ wfrag) {
    const int idx = blockIdx.x * 256 + threadIdx.x;  // 24 blocks * 256 = 6144
    const int row = idx >> 5;        // W row (= output col), 0..191
    const int k2  = idx & 31;        // k/2
    const int ct  = row >> 4;
    const int c   = row & 15;
    const int ks  = k2 >> 4;
    const int lhi = (k2 >> 2) & 3;   // (k>>3)&3
    const int lane = c + (lhi << 4);
    const int slot = k2 & 3;         // (k&7)>>1
    const int fo = (((ct << 1) + ks) << 8) + (lane << 2) + slot;
    const float2 wi = *(const float2*)(Wih + (row << 6) + (k2 << 1));
    const float2 wh = *(const float2*)(Whh + (row << 6) + (k2 << 1));
    wfrag[fo]            = bf16rne(wi.x) | (bf16rne(wi.y) << 16);
    wfrag[24 * 256 + fo] = bf16rne(wh.x) | (bf16rne(wh.y) << 16);
}

// ---- GRU cell via MFMA --------------------------------------------------
// One wave per 16-node group; 96 mfma_f32_16x16x32_bf16 per wave; no LDS.
// C layout (m89): col = lane&15, row = 4*(lane>>4) + reg.
__global__ __launch_bounds__(256) void gru_k(
    const float* hnew, const float* __restrict__ h,
    const unsigned* __restrict__ wfrag,
    const float* __restrict__ bih, const float* __restrict__ bhh,
    float* out)
{
    const int tid  = threadIdx.x;
    const int wid  = tid >> 6;
    const int lane = tid & 63;
    const int grp  = blockIdx.x * 4 + wid;
    if (grp >= NGRP) return;
    const int base = grp << 4;

    const int rA   = lane & 15;
    const int koff = (lane >> 4) << 3;

    const float* xr = hnew + ((base + rA) << 6);
    const float* hr = h    + ((base + rA) << 6);

    short8_t ax[2], ah[2];
    #pragma unroll
    for (int ks = 0; ks < 2; ++ks) {
        const float4 x0 = *(const float4*)(xr + ks * 32 + koff);
        const float4 x1 = *(const float4*)(xr + ks * 32 + koff + 4);
        const float4 h0 = *(const float4*)(hr + ks * 32 + koff);
        const float4 h1 = *(const float4*)(hr + ks * 32 + koff + 4);
        ax[ks] = pack8(x0, x1);
        ah[ks] = pack8(h0, h1);
    }

    f32x4 acc[24];
    #pragma unroll
    for (int i = 0; i < 24; ++i) acc[i] = (f32x4){0.f, 0.f, 0.f, 0.f};

    const unsigned* wf = wfrag + (lane << 2);
    #pragma unroll
    for (int ct = 0; ct < 12; ++ct) {
        const short8_t b0 = *(const short8_t*)(wf + (((ct << 1)     ) << 8));
        const short8_t b1 = *(const short8_t*)(wf + (((ct << 1) + 1) << 8));
        const short8_t c0 = *(const short8_t*)(wf + ((24 + (ct << 1)    ) << 8));
        const short8_t c1 = *(const short8_t*)(wf + ((24 + (ct << 1) + 1) << 8));
        acc[ct]      = __builtin_amdgcn_mfma_f32_16x16x32_bf16(ax[0], b0, acc[ct],      0, 0, 0);
        acc[ct]      = __builtin_amdgcn_mfma_f32_16x16x32_bf16(ax[1], b1, acc[ct],      0, 0, 0);
        acc[12 + ct] = __builtin_amdgcn_mfma_f32_16x16x32_bf16(ah[0], c0, acc[12 + ct], 0, 0, 0);
        acc[12 + ct] = __builtin_amdgcn_mfma_f32_16x16x32_bf16(ah[1], c1, acc[12 + ct], 0, 0, 0);
    }

    const int rnode = base + ((lane >> 4) << 2);
    const int c     = lane & 15;
    #pragma unroll
    for (int ct = 0; ct < 4; ++ct) {
        const int ch = (ct << 4) + c;
        const float brz = bih[ch] + bhh[ch];
        const float bzz = bih[64 + ch] + bhh[64 + ch];
        const float bin = bih[128 + ch];
        const float bhn = bhh[128 + ch];
        #pragma unroll
        for (int r = 0; r < 4; ++r) {
            const int node = rnode + r;
            const float rr = fsig(acc[ct][r] + acc[12 + ct][r] + brz);
            const float zz = fsig(acc[4 + ct][r] + acc[16 + ct][r] + bzz);
            const float hn = acc[20 + ct][r] + bhn;
            const float nn = ftanh(fmaf(rr, hn, acc[8 + ct][r] + bin));
            const float hv = h[(node << 6) + ch];
            out[(node << 6) + ch] = fmaf(zz, hv - nn, nn);  // (1-z)*n + z*h
        }
    }
}

extern "C" void kernel_launch(void* const* d_in, const int* in_sizes, int n_in,
                              void* d_out, int out_size, void* d_ws, size_t ws_size,
                              hipStream_t stream)
{
    const float* h   = (const float*)d_in[0];
    const float* ew  = (const float*)d_in[1];
    const float* Wih = (const float*)d_in[2];
    const float* Whh = (const float*)d_in[3];
    const float* bih = (const float*)d_in[4];
    const float* bhh = (const float*)d_in[5];
    const int*   src = (const int*)d_in[6];
    const int*   dst = (const int*)d_in[7];
    float* out = (float*)d_out;

    // ws layout (~23.4 MB, under the 25.6 MB proven available)
    char* ws = (char*)d_ws;
    unsigned*       gcnt   = (unsigned*)      (ws);              //   2,048 B
    unsigned*       ovcnt  = (unsigned*)      (ws + 2048);       //      64 B
    unsigned*       wfrag  = (unsigned*)      (ws + 2112);       //  49,152 B
    unsigned*       binkey = (unsigned*)      (ws + 65536);      // 7,206,912 B
    unsigned short* binwgt = (unsigned short*)(ws + 7272448);    // 3,603,456 B
    unsigned*       ov_key = (unsigned*)      (ws + 10875904);   //  16,384 B
    unsigned short* ov_wgt = (unsigned short*)(ws + 10892288);   //   8,192 B
    unsigned*       ov_b   = (unsigned*)      (ws + 10900480);   //  16,384 B
    unsigned*       deg    = (unsigned*)      (ws + 10916864);   // 400,000 B
    unsigned*       cursor = (unsigned*)      (ws + 11316864);   // 400,000 B
    unsigned*       hb     = (unsigned*)      (ws + 11716864);   // 12,800,000 B -> 24,516,864

    hipMemsetAsync(ws, 0, 2112, stream);                    // gcnt + ovcnt
    hcvt_k <<<12500, 256, 0, stream>>>(h, hb);
    wprep_k<<<24, 256, 0, stream>>>(Wih, Whh, wfrag);
    bin_k  <<<NBIN, 512, 0, stream>>>(src, dst, ew, gcnt, binkey, binwgt,
                                      ovcnt, ov_key, ov_wgt, ov_b);
    sort_k <<<NBKT, 512, 0, stream>>>(binkey, binwgt, gcnt, ovcnt,
                                      ov_key, ov_wgt, ov_b, cursor, deg);
    segsum_k<<<NN / 4, 256, 0, stream>>>(hb, binkey, binwgt, cursor, deg, out);
    gru_k  <<<NBGRU, 256, 0, stream>>>(out, h, wfrag, bih, bhh, out);
}